// Round 11
// baseline (111.843 us; speedup 1.0000x reference)
//
#include <hip/hip_runtime.h>

// Rec1_43748536877661 — diagonal SSM block, MI355X gfx950.
// B=2,S=2048,D=128,N=2048. fp32 in/out, bf16 MFMA compute (tol 2.14e-2).
// R20: R19 (110.99us) + outproj 8-wave x 8-step restructure.
// R19 VALIDATED the outproj latency-bound theory (d-split -> 2 blocks/CU:
// -4.1us, matched prediction). This extends the same mechanism at zero
// added traffic: block 512 (8 waves), wave wv does kk in [wv*8,wv*8+8),
// dt = half*4+0..3. Serial dependent-chain depth 16->8, waves/CU 8->16,
// no extra ybp duplication (unlike a 4-way d-split). Reduction 4->8
// partials (32KB LDS, 2 blocks/CU).
// projscan/prep byte-for-byte R18 (session-proven best; 7 probes showed
// sync ~free, time tracks work, latency floor resists source-level attack).
//  1. prep      pack x,W_B/dt/C,W_out fragment-linear bf16; Aval; zero Sbuf
//  2. projscan  grid(16,64): GEMM+scan local, publish local agg, decoupled
//               lookback, fixup -> y (bf16 A-frag)
//  3. outproj   grid(256,2) x 512thr: y @ W_out^T + b_out -> fp32 out
// Deadlock safety: waiter at row position j targets positions <j whose
// swizzled linear ids are strictly smaller (dispatched earlier; publish is
// unconditional after Phase A) -> acyclic for ANY id->XCD mapping.

#define BB 2
#define SS 2048
#define DDIM 128
#define NDIM 2048
#define TT (BB*SS)        // 4096 tokens
#define NTILE (TT/16)     // 256 t-tiles

typedef short short8 __attribute__((ext_vector_type(8)));
typedef float floatx4 __attribute__((ext_vector_type(4)));

__device__ __forceinline__ unsigned short f2b(float f){
  unsigned u = __float_as_uint(f);
  u += 0x7FFFu + ((u >> 16) & 1u);
  return (unsigned short)(u >> 16);
}
__device__ __forceinline__ unsigned cvt_pk_bf16(float lo, float hi){
  unsigned r;
  asm("v_cvt_pk_bf16_f32 %0, %1, %2" : "=v"(r) : "v"(lo), "v"(hi));
  return r;
}
__device__ __forceinline__ float softplus_f(float v){
  return v > 15.f ? v : __logf(1.f + __expf(v));
}
__device__ __forceinline__ void pack8(const float* __restrict__ s,
                                      unsigned short* __restrict__ d){
  floatx4 v0 = *(const floatx4*)s;
  floatx4 v1 = *(const floatx4*)(s + 4);
  short8 r;
  r[0]=(short)f2b(v0[0]); r[1]=(short)f2b(v0[1]); r[2]=(short)f2b(v0[2]); r[3]=(short)f2b(v0[3]);
  r[4]=(short)f2b(v1[0]); r[5]=(short)f2b(v1[1]); r[6]=(short)f2b(v1[2]); r[7]=(short)f2b(v1[3]);
  *(short8*)d = r;
}

// ---------------- 1. prep ----------------
__global__ void prep_kernel(const float* __restrict__ x,
                            const float* __restrict__ W_B,
                            const float* __restrict__ W_C,
                            const float* __restrict__ W_dt,
                            const float* __restrict__ A_log,
                            const float* __restrict__ W_out,
                            unsigned short* __restrict__ xp,
                            unsigned short* __restrict__ Wp3,
                            unsigned short* __restrict__ Wop,
                            float* __restrict__ Aval,
                            unsigned long long* __restrict__ Sbuf){
  const int gid = blockIdx.x * blockDim.x + threadIdx.x;   // 0..98303
  if (gid < 32768) Sbuf[gid] = 0ull;              // clear (1024 entries x 32 n)
  if (gid < 2048) Aval[gid] = -__expf(A_log[gid]);
  if (gid < 65536){                               // x: 256 t-tiles, K=128
    int g = gid, tile = g >> 8, kk = (g >> 6) & 3, lane = g & 63;
    int q = lane >> 4, m = lane & 15;
    pack8(x + (size_t)(tile*16 + m)*DDIM + kk*32 + q*8, xp + (size_t)g*8);
  }
  if (gid < 98304){                               // W_B/W_dt/W_C: 128 n-tiles each
    int mat = gid >> 15, g = gid & 32767;
    const float* W = (mat == 0) ? W_B : (mat == 1 ? W_dt : W_C);
    int tile = g >> 8, kk = (g >> 6) & 3, lane = g & 63;
    int q = lane >> 4, m = lane & 15;
    pack8(W + (size_t)(tile*16 + m)*DDIM + kk*32 + q*8,
          Wp3 + (size_t)mat*262144 + (size_t)g*8);
  }
  if (gid < 32768){                               // W_out: 8 d-tiles, K=2048
    int g = gid, tile = g >> 12, kk = (g >> 6) & 63, lane = g & 63;
    int q = lane >> 4, m = lane & 15;
    pack8(W_out + (size_t)(tile*16 + m)*NDIM + kk*32 + q*8, Wop + (size_t)g*8);
  }
}

// ---------------- 2. projscan, XCD-local decoupled lookback ----------------
// grid (16, 64), block 256. Physical id p = by*16+bx is swizzled:
//   xcd=p&7, slot=p>>3, rr=slot&15, j=slot>>4, row=xcd*16+rr
//   by=row>>1, bx=(row&1)*8+j   (j = position within the 8-block chain row)
// (256,2): VGPR budget 256 -> natural ~88-110, NO spill (R10 lesson).
__global__ __launch_bounds__(256, 2) void projscan_kernel(
    const unsigned short* __restrict__ xp,
    const unsigned short* __restrict__ Wp3,
    const float* __restrict__ b_B,
    const float* __restrict__ b_dt,
    const float* __restrict__ b_C,
    const float* __restrict__ Aval,
    unsigned long long* __restrict__ Sbuf,   // [64*16][32] packed (P|H)
    unsigned short* __restrict__ ybp){
  __shared__ unsigned short sW[3*4096];      // 24 KB packed weights (Phase A)
  // sYT aliases the first 5 KB of sW: sW is dead after the Phase-A barrier,
  // sYT is written only after the Phase-B barrier. 4 waves x 640 ushorts.
  __shared__ float sPw[4][32], sHw[4][32];   // per-wave chain totals
  __shared__ float sIw[4][32];               // per-wave init states
  const int tid  = threadIdx.x;
  const int lane = tid & 63;
  const int wv   = tid >> 6;
  const int m    = lane & 15;
  const int q    = lane >> 4;
  // --- XCD-local row swizzle ---
  const int p    = blockIdx.y * 16 + blockIdx.x;  // dispatch-linear id
  const int xcd  = p & 7;
  const int slot = p >> 3;                        // 0..127
  const int rr   = slot & 15;
  const int j    = slot >> 4;                     // 0..7 position in row
  const int row  = xcd*16 + rr;                   // 0..127
  const int by   = row >> 1;                      // n-slice 0..63
  const int bx   = (row & 1)*8 + j;               // t-chunk 0..15
  const int n0   = by*32;
  unsigned short* sYT = sW + wv*640;              // Phase-C scratch (alias)

  // stage packed weights: 3 mats x 2 n-tiles x 2048 ushort
  for (int i = tid; i < 1536; i += 256){
    int mat = i >> 9, rem = i & 511;
    *(short8*)(sW + mat*4096 + rem*8) =
        *(const short8*)(Wp3 + (size_t)mat*262144 + (size_t)by*4096 + rem*8);
  }
  __syncthreads();

  // per-nt biases (n = n0 + nt*16 + m)
  float bBv[2], bDv[2], bCv[2], Avv[2];
#pragma unroll
  for (int nt = 0; nt < 2; ++nt){
    const int n = n0 + nt*16 + m;
    bBv[nt] = b_B[n]; bDv[nt] = b_dt[n]; bCv[nt] = b_C[n]; Avv[nt] = Aval[n];
  }

  // ---- Phase A: 4 sequential tiles, local scan (init 0), keep y/coef packed
  unsigned ypk[4][2][2], cpk[4][2][2];
  float pe_t[4][2], he_t[4][2];
  float pa_run[2] = {1.f, 1.f}, ha_run[2] = {0.f, 0.f};

  short8 xf[2][4];                           // ping-pong prefetch buffers
  {
    const int t0 = bx*16 + wv*4;
#pragma unroll
    for (int kk = 0; kk < 4; ++kk)
      xf[0][kk] = *(const short8*)(xp + (size_t)t0*2048 + kk*512 + lane*8);
  }

#pragma unroll
  for (int i = 0; i < 4; ++i){
    const int cur = i & 1;                   // constant after unroll
    floatx4 acc[3][2];
#pragma unroll
    for (int mat = 0; mat < 3; ++mat)
#pragma unroll
      for (int nt = 0; nt < 2; ++nt)
        acc[mat][nt] = (floatx4){0.f,0.f,0.f,0.f};
#pragma unroll
    for (int nt = 0; nt < 2; ++nt)
#pragma unroll
      for (int kk = 0; kk < 4; ++kk){
        short8 wB = *(const short8*)(sW +         nt*2048 + kk*512 + lane*8);
        short8 wD = *(const short8*)(sW + 4096 +  nt*2048 + kk*512 + lane*8);
        short8 wC = *(const short8*)(sW + 8192 +  nt*2048 + kk*512 + lane*8);
        acc[0][nt] = __builtin_amdgcn_mfma_f32_16x16x32_bf16(xf[cur][kk], wB, acc[0][nt], 0, 0, 0);
        acc[1][nt] = __builtin_amdgcn_mfma_f32_16x16x32_bf16(xf[cur][kk], wD, acc[1][nt], 0, 0, 0);
        acc[2][nt] = __builtin_amdgcn_mfma_f32_16x16x32_bf16(xf[cur][kk], wC, acc[2][nt], 0, 0, 0);
      }
    // prefetch next tile's x fragments NOW, so the L2 round-trip hides
    // under the scan's trans/shuffle chain below
    if (i < 3){
      const int t1 = bx*16 + wv*4 + i + 1;
#pragma unroll
      for (int kk = 0; kk < 4; ++kk)
        xf[cur^1][kk] = *(const short8*)(xp + (size_t)t1*2048 + kk*512 + lane*8);
    }

#pragma unroll
    for (int nt = 0; nt < 2; ++nt){
      float Ar[4], Br[4], Cc[4];
#pragma unroll
      for (int r = 0; r < 4; ++r){
        float dtv = softplus_f(acc[1][nt][r] + bDv[nt]);
        Ar[r] = __expf(dtv * Avv[nt]);
        Br[r] = dtv * (acc[0][nt][r] + bBv[nt]);
        Cc[r] = acc[2][nt][r] + bCv[nt];
      }
      // compose lane's 4-token segment
      float P = Ar[0], H = Br[0];
#pragma unroll
      for (int r = 1; r < 4; ++r){ H = Ar[r]*H + Br[r]; P *= Ar[r]; }
      // inclusive scan across q (2 steps)
      float pp = __shfl(P, (lane - 16) & 63, 64);
      float hh = __shfl(H, (lane - 16) & 63, 64);
      if (q >= 1){ H = P*hh + H; P *= pp; }
      pp = __shfl(P, (lane - 32) & 63, 64);
      hh = __shfl(H, (lane - 32) & 63, 64);
      if (q >= 2){ H = P*hh + H; P *= pp; }
      // exclusive prefix for this q
      float pe = __shfl(P, (lane - 16) & 63, 64);
      float he = __shfl(H, (lane - 16) & 63, 64);
      if (q == 0){ pe = 1.f; he = 0.f; }
      // tile totals broadcast (q==3 inclusive)
      float pb = __shfl(P, m + 48, 64);
      float hb = __shfl(H, m + 48, 64);

      float h = he, pa = pe;
      float ys[4], cs[4];
#pragma unroll
      for (int r = 0; r < 4; ++r){
        h = Ar[r]*h + Br[r];
        pa *= Ar[r];
        ys[r] = Cc[r]*h;
        cs[r] = Cc[r]*pa;
      }
      ypk[i][nt][0] = cvt_pk_bf16(ys[0], ys[1]);
      ypk[i][nt][1] = cvt_pk_bf16(ys[2], ys[3]);
      cpk[i][nt][0] = cvt_pk_bf16(cs[0], cs[1]);
      cpk[i][nt][1] = cvt_pk_bf16(cs[2], cs[3]);

      pe_t[i][nt] = pa_run[nt];
      he_t[i][nt] = ha_run[nt];
      ha_run[nt] = pb*ha_run[nt] + hb;
      pa_run[nt] *= pb;
    }
  }
  // publish wave totals per n (identical across q; q==0 writes)
  if (q == 0){
#pragma unroll
    for (int nt = 0; nt < 2; ++nt){
      sPw[wv][nt*16 + m] = pa_run[nt];
      sHw[wv][nt*16 + m] = ha_run[nt];
    }
  }
  __syncthreads();                           // sW dead from here

  // ---- Phase B: publish LOCAL aggregate, decoupled lookback (threads 0..31)
  if (tid < 32){
    float Pw[4], Hw[4];
#pragma unroll
    for (int w2 = 0; w2 < 4; ++w2){ Pw[w2] = sPw[w2][tid]; Hw[w2] = sHw[w2][tid]; }
    // block-local aggregate over the 4 waves
    float pb = 1.f, hb = 0.f;
#pragma unroll
    for (int w2 = 0; w2 < 4; ++w2){ hb = Pw[w2]*hb + Hw[w2]; pb *= Pw[w2]; }
    // single-word publish: [P|H]; validity = P bits != 0 (P>0, clamped)
    float pbc = fmaxf(pb, 1e-30f);
    __hip_atomic_store(Sbuf + (size_t)(by*16 + bx)*32 + tid,
        ((unsigned long long)__float_as_uint(pbc) << 32) |
         (unsigned long long)__float_as_uint(hb),
        __ATOMIC_RELAXED, __HIP_MEMORY_SCOPE_AGENT);
    // gather ALL predecessors' locals concurrently. Backoff sleep: waiters
    // must NOT flood L2 with polls -- that starves workers' xp loads.
    float S = 0.f;
    const int cnt = bx & 7;                // # predecessors within batch row
    if (cnt){
      const int j0 = bx & ~7;
      unsigned long long v0=0,v1=0,v2=0,v3=0,v4=0,v5=0,v6=0;
      unsigned got = 0;
      int spin = 0;
      const unsigned all = (1u << cnt) - 1u;
      const unsigned long long* base = Sbuf + (size_t)(by*16 + j0)*32 + tid;
      for (;;){
#define LOOKBACK(J, V)                                                          \
        if (J < cnt && !(got & (1u << J))){                                     \
          unsigned long long a = __hip_atomic_load(base + (size_t)J*32,         \
              __ATOMIC_RELAXED, __HIP_MEMORY_SCOPE_AGENT);                      \
          if ((unsigned)(a >> 32) != 0u){ V = a; got |= 1u << J; }              \
        }
        LOOKBACK(0, v0) LOOKBACK(1, v1) LOOKBACK(2, v2) LOOKBACK(3, v3)
        LOOKBACK(4, v4) LOOKBACK(5, v5) LOOKBACK(6, v6)
#undef LOOKBACK
        if (got == all) break;
        if (spin < 4)       __builtin_amdgcn_s_sleep(2);
        else if (spin < 8)  __builtin_amdgcn_s_sleep(8);
        else                __builtin_amdgcn_s_sleep(32);
        ++spin;
      }
      // ordered composition j0..bx-1: S = P_j*S + H_j
#define COMPOSE(J, V)                                                           \
      if (J < cnt) S = __uint_as_float((unsigned)(V >> 32))*S +                 \
                       __uint_as_float((unsigned)V);
      COMPOSE(0, v0) COMPOSE(1, v1) COMPOSE(2, v2) COMPOSE(3, v3)
      COMPOSE(4, v4) COMPOSE(5, v5) COMPOSE(6, v6)
#undef COMPOSE
    }
    // per-wave init states
    float s = S;
#pragma unroll
    for (int w2 = 0; w2 < 4; ++w2){
      sIw[w2][tid] = s;
      s = Pw[w2]*s + Hw[w2];
    }
  }
  __syncthreads();                           // sYT (alias of sW) live from here

  // ---- Phase C: fixup + transpose + store
  float iw[2];
#pragma unroll
  for (int nt = 0; nt < 2; ++nt) iw[nt] = sIw[wv][nt*16 + m];
#pragma unroll
  for (int i = 0; i < 4; ++i){
    const int tile = bx*16 + wv*4 + i;
#pragma unroll
    for (int nt = 0; nt < 2; ++nt){
      float it = pe_t[i][nt]*iw[nt] + he_t[i][nt];
#pragma unroll
      for (int j2 = 0; j2 < 2; ++j2){
        unsigned yp = ypk[i][nt][j2], cp = cpk[i][nt][j2];
        float y0 = __uint_as_float(yp << 16);
        float y1 = __uint_as_float(yp & 0xffff0000u);
        float c0 = __uint_as_float(cp << 16);
        float c1 = __uint_as_float(cp & 0xffff0000u);
        sYT[(q*4 + j2*2 + 0)*40 + nt*16 + m] = f2b(y0 + c0*it);
        sYT[(q*4 + j2*2 + 1)*40 + nt*16 + m] = f2b(y1 + c1*it);
      }
    }
    short8 yv = *(const short8*)&sYT[m*40 + q*8];
    *(short8*)(ybp + (size_t)tile*32768 + (size_t)by*512 + (size_t)lane*8) = yv;
  }
}

// ---------------- 3. output projection, d-split + 8-wave ----------------
// grid (NTILE, 2), block 512 (8 waves). Block (tile, half): d-tiles
// dt = half*4 .. half*4+3; wave wv: kk in [wv*8, wv*8+8).
// vs R19: serial dependent-chain depth 16->8, waves/CU 8->16, traffic
// unchanged. LDS 32 KB (8 partials x 1024), 2 blocks/CU.
__global__ __launch_bounds__(512, 1) void outproj_kernel(
    const unsigned short* __restrict__ ybp,
    const unsigned short* __restrict__ Wop,
    const float* __restrict__ b_out,
    float* __restrict__ out){
  __shared__ float red[8*1024];          // 8 waves x 16 tl x 64 d_local
  const int tid  = threadIdx.x;
  const int lane = tid & 63;
  const int wv   = tid >> 6;             // 0..7
  const int m    = lane & 15;
  const int q    = lane >> 4;
  const int tile = blockIdx.x;
  const int half = blockIdx.y;           // d-half: dt = half*4 + dtl

  floatx4 acc[4];
#pragma unroll
  for (int dtl = 0; dtl < 4; ++dtl) acc[dtl] = (floatx4){0.f,0.f,0.f,0.f};

  const unsigned short* aP = ybp + (size_t)tile*32768 + lane*8;
  const unsigned short* bP = Wop + (size_t)(half*4)*32768 + lane*8;
#pragma unroll
  for (int kk = wv*8; kk < wv*8 + 8; ++kk){
    short8 af = *(const short8*)(aP + (size_t)kk*512);
#pragma unroll
    for (int dtl = 0; dtl < 4; ++dtl){
      short8 bf = *(const short8*)(bP + (size_t)dtl*32768 + (size_t)kk*512);
      acc[dtl] = __builtin_amdgcn_mfma_f32_16x16x32_bf16(af, bf, acc[dtl], 0, 0, 0);
    }
  }
#pragma unroll
  for (int dtl = 0; dtl < 4; ++dtl)
#pragma unroll
    for (int r = 0; r < 4; ++r)
      red[wv*1024 + (q*4 + r)*64 + dtl*16 + m] = acc[dtl][r];
  __syncthreads();
#pragma unroll
  for (int i = 0; i < 2; ++i){
    int idx = i*512 + tid;                        // 0..1023 = tl*64 + dl
    float s = red[idx]        + red[1024 + idx] + red[2048 + idx] + red[3072 + idx]
            + red[4096 + idx] + red[5120 + idx] + red[6144 + idx] + red[7168 + idx];
    int tl = idx >> 6, dl = idx & 63;
    int d = half*64 + dl;
    out[(size_t)(tile*16 + tl)*DDIM + d] = s + b_out[d];
  }
}

extern "C" void kernel_launch(void* const* d_in, const int* in_sizes, int n_in,
                              void* d_out, int out_size, void* d_ws, size_t ws_size,
                              hipStream_t stream) {
  const float* x     = (const float*)d_in[0];
  const float* W_B   = (const float*)d_in[1];
  const float* b_B   = (const float*)d_in[2];
  const float* W_C   = (const float*)d_in[3];
  const float* b_C   = (const float*)d_in[4];
  const float* W_dt  = (const float*)d_in[5];
  const float* b_dt  = (const float*)d_in[6];
  const float* A_log = (const float*)d_in[7];
  const float* W_out = (const float*)d_in[8];
  const float* b_out = (const float*)d_in[9];
  float* out = (float*)d_out;

  char* w = (char*)d_ws;
  unsigned short* xp    = (unsigned short*)(w + 0x0000000);  // 1 MB
  unsigned short* Wp3   = (unsigned short*)(w + 0x0100000);  // 1.5 MB
  unsigned short* Wop   = (unsigned short*)(w + 0x0280000);  // 0.5 MB
  float*          Aval  = (float*)         (w + 0x0300000);  // 8 KB
  unsigned short* ybp   = (unsigned short*)(w + 0x0310000);  // 16 MB
  unsigned long long* Sbuf = (unsigned long long*)(w + 0x1310000); // 256 KB
  // total ~19.7 MB

  prep_kernel<<<384, 256, 0, stream>>>(
      x, W_B, W_C, W_dt, A_log, W_out, xp, Wp3, Wop, Aval, Sbuf);

  projscan_kernel<<<dim3(16, 64), 256, 0, stream>>>(
      xp, Wp3, b_B, b_dt, b_C, Aval, Sbuf, ybp);

  outproj_kernel<<<dim3(NTILE, 2), 512, 0, stream>>>(ybp, Wop, b_out, out);
}

// Round 12
// 109.367 us; speedup vs baseline: 1.0226x; 1.0226x over previous
//
#include <hip/hip_runtime.h>

// Rec1_43748536877661 — diagonal SSM block, MI355X gfx950.
// B=2,S=2048,D=128,N=2048. fp32 in/out, bf16 MFMA compute (tol 2.14e-2).
// R21 = FINAL: resubmit of R19 (session best, 110.99us).
// Ledger: R9 handoff 119.6 -> R19 110.99 (-7.2%). Wins: R11/R12 lookback
// decoupling+XCD-local (-4 combined), R19 outproj d-split (-4.1, latency
// theory validated by matched prediction). Nulls/regressions: R10 spill
// (+21), R13 micro-bundle (0), R15 fused 2-pass (+2.8), R16 zero-sync
// split (+9.1), R17 wave-decoupled (+5), R20 outproj 8-wave (+0.85).
// Floors established: projscan (7 probes: sync ~free, time tracks work),
// outproj (R19 win + R20 null = L2-BW/latency floor ~5us). ~88us of the
// timed window is harness poison fills (2 x ~44us), not addressable.
//  1. prep      pack x,W_B/dt/C,W_out fragment-linear bf16; Aval; zero Sbuf
//  2. projscan  grid(16,64): GEMM+scan local, publish local agg, decoupled
//               lookback, fixup -> y (bf16 A-frag)
//  3. outproj   grid(256,2): y @ W_out^T + b_out -> fp32 out (2 blocks/CU)
// Deadlock safety: waiter at row position j targets positions <j whose
// swizzled linear ids are strictly smaller (dispatched earlier; publish is
// unconditional after Phase A) -> acyclic for ANY id->XCD mapping.

#define BB 2
#define SS 2048
#define DDIM 128
#define NDIM 2048
#define TT (BB*SS)        // 4096 tokens
#define NTILE (TT/16)     // 256 t-tiles

typedef short short8 __attribute__((ext_vector_type(8)));
typedef float floatx4 __attribute__((ext_vector_type(4)));

__device__ __forceinline__ unsigned short f2b(float f){
  unsigned u = __float_as_uint(f);
  u += 0x7FFFu + ((u >> 16) & 1u);
  return (unsigned short)(u >> 16);
}
__device__ __forceinline__ unsigned cvt_pk_bf16(float lo, float hi){
  unsigned r;
  asm("v_cvt_pk_bf16_f32 %0, %1, %2" : "=v"(r) : "v"(lo), "v"(hi));
  return r;
}
__device__ __forceinline__ float softplus_f(float v){
  return v > 15.f ? v : __logf(1.f + __expf(v));
}
__device__ __forceinline__ void pack8(const float* __restrict__ s,
                                      unsigned short* __restrict__ d){
  floatx4 v0 = *(const floatx4*)s;
  floatx4 v1 = *(const floatx4*)(s + 4);
  short8 r;
  r[0]=(short)f2b(v0[0]); r[1]=(short)f2b(v0[1]); r[2]=(short)f2b(v0[2]); r[3]=(short)f2b(v0[3]);
  r[4]=(short)f2b(v1[0]); r[5]=(short)f2b(v1[1]); r[6]=(short)f2b(v1[2]); r[7]=(short)f2b(v1[3]);
  *(short8*)d = r;
}

// ---------------- 1. prep ----------------
__global__ void prep_kernel(const float* __restrict__ x,
                            const float* __restrict__ W_B,
                            const float* __restrict__ W_C,
                            const float* __restrict__ W_dt,
                            const float* __restrict__ A_log,
                            const float* __restrict__ W_out,
                            unsigned short* __restrict__ xp,
                            unsigned short* __restrict__ Wp3,
                            unsigned short* __restrict__ Wop,
                            float* __restrict__ Aval,
                            unsigned long long* __restrict__ Sbuf){
  const int gid = blockIdx.x * blockDim.x + threadIdx.x;   // 0..98303
  if (gid < 32768) Sbuf[gid] = 0ull;              // clear (1024 entries x 32 n)
  if (gid < 2048) Aval[gid] = -__expf(A_log[gid]);
  if (gid < 65536){                               // x: 256 t-tiles, K=128
    int g = gid, tile = g >> 8, kk = (g >> 6) & 3, lane = g & 63;
    int q = lane >> 4, m = lane & 15;
    pack8(x + (size_t)(tile*16 + m)*DDIM + kk*32 + q*8, xp + (size_t)g*8);
  }
  if (gid < 98304){                               // W_B/W_dt/W_C: 128 n-tiles each
    int mat = gid >> 15, g = gid & 32767;
    const float* W = (mat == 0) ? W_B : (mat == 1 ? W_dt : W_C);
    int tile = g >> 8, kk = (g >> 6) & 3, lane = g & 63;
    int q = lane >> 4, m = lane & 15;
    pack8(W + (size_t)(tile*16 + m)*DDIM + kk*32 + q*8,
          Wp3 + (size_t)mat*262144 + (size_t)g*8);
  }
  if (gid < 32768){                               // W_out: 8 d-tiles, K=2048
    int g = gid, tile = g >> 12, kk = (g >> 6) & 63, lane = g & 63;
    int q = lane >> 4, m = lane & 15;
    pack8(W_out + (size_t)(tile*16 + m)*NDIM + kk*32 + q*8, Wop + (size_t)g*8);
  }
}

// ---------------- 2. projscan, XCD-local decoupled lookback ----------------
// grid (16, 64), block 256. Physical id p = by*16+bx is swizzled:
//   xcd=p&7, slot=p>>3, rr=slot&15, j=slot>>4, row=xcd*16+rr
//   by=row>>1, bx=(row&1)*8+j   (j = position within the 8-block chain row)
// (256,2): VGPR budget 256 -> natural ~88-110, NO spill (R10 lesson).
__global__ __launch_bounds__(256, 2) void projscan_kernel(
    const unsigned short* __restrict__ xp,
    const unsigned short* __restrict__ Wp3,
    const float* __restrict__ b_B,
    const float* __restrict__ b_dt,
    const float* __restrict__ b_C,
    const float* __restrict__ Aval,
    unsigned long long* __restrict__ Sbuf,   // [64*16][32] packed (P|H)
    unsigned short* __restrict__ ybp){
  __shared__ unsigned short sW[3*4096];      // 24 KB packed weights (Phase A)
  // sYT aliases the first 5 KB of sW: sW is dead after the Phase-A barrier,
  // sYT is written only after the Phase-B barrier. 4 waves x 640 ushorts.
  __shared__ float sPw[4][32], sHw[4][32];   // per-wave chain totals
  __shared__ float sIw[4][32];               // per-wave init states
  const int tid  = threadIdx.x;
  const int lane = tid & 63;
  const int wv   = tid >> 6;
  const int m    = lane & 15;
  const int q    = lane >> 4;
  // --- XCD-local row swizzle ---
  const int p    = blockIdx.y * 16 + blockIdx.x;  // dispatch-linear id
  const int xcd  = p & 7;
  const int slot = p >> 3;                        // 0..127
  const int rr   = slot & 15;
  const int j    = slot >> 4;                     // 0..7 position in row
  const int row  = xcd*16 + rr;                   // 0..127
  const int by   = row >> 1;                      // n-slice 0..63
  const int bx   = (row & 1)*8 + j;               // t-chunk 0..15
  const int n0   = by*32;
  unsigned short* sYT = sW + wv*640;              // Phase-C scratch (alias)

  // stage packed weights: 3 mats x 2 n-tiles x 2048 ushort
  for (int i = tid; i < 1536; i += 256){
    int mat = i >> 9, rem = i & 511;
    *(short8*)(sW + mat*4096 + rem*8) =
        *(const short8*)(Wp3 + (size_t)mat*262144 + (size_t)by*4096 + rem*8);
  }
  __syncthreads();

  // per-nt biases (n = n0 + nt*16 + m)
  float bBv[2], bDv[2], bCv[2], Avv[2];
#pragma unroll
  for (int nt = 0; nt < 2; ++nt){
    const int n = n0 + nt*16 + m;
    bBv[nt] = b_B[n]; bDv[nt] = b_dt[n]; bCv[nt] = b_C[n]; Avv[nt] = Aval[n];
  }

  // ---- Phase A: 4 sequential tiles, local scan (init 0), keep y/coef packed
  unsigned ypk[4][2][2], cpk[4][2][2];
  float pe_t[4][2], he_t[4][2];
  float pa_run[2] = {1.f, 1.f}, ha_run[2] = {0.f, 0.f};

  short8 xf[2][4];                           // ping-pong prefetch buffers
  {
    const int t0 = bx*16 + wv*4;
#pragma unroll
    for (int kk = 0; kk < 4; ++kk)
      xf[0][kk] = *(const short8*)(xp + (size_t)t0*2048 + kk*512 + lane*8);
  }

#pragma unroll
  for (int i = 0; i < 4; ++i){
    const int cur = i & 1;                   // constant after unroll
    floatx4 acc[3][2];
#pragma unroll
    for (int mat = 0; mat < 3; ++mat)
#pragma unroll
      for (int nt = 0; nt < 2; ++nt)
        acc[mat][nt] = (floatx4){0.f,0.f,0.f,0.f};
#pragma unroll
    for (int nt = 0; nt < 2; ++nt)
#pragma unroll
      for (int kk = 0; kk < 4; ++kk){
        short8 wB = *(const short8*)(sW +         nt*2048 + kk*512 + lane*8);
        short8 wD = *(const short8*)(sW + 4096 +  nt*2048 + kk*512 + lane*8);
        short8 wC = *(const short8*)(sW + 8192 +  nt*2048 + kk*512 + lane*8);
        acc[0][nt] = __builtin_amdgcn_mfma_f32_16x16x32_bf16(xf[cur][kk], wB, acc[0][nt], 0, 0, 0);
        acc[1][nt] = __builtin_amdgcn_mfma_f32_16x16x32_bf16(xf[cur][kk], wD, acc[1][nt], 0, 0, 0);
        acc[2][nt] = __builtin_amdgcn_mfma_f32_16x16x32_bf16(xf[cur][kk], wC, acc[2][nt], 0, 0, 0);
      }
    // prefetch next tile's x fragments NOW, so the L2 round-trip hides
    // under the scan's trans/shuffle chain below
    if (i < 3){
      const int t1 = bx*16 + wv*4 + i + 1;
#pragma unroll
      for (int kk = 0; kk < 4; ++kk)
        xf[cur^1][kk] = *(const short8*)(xp + (size_t)t1*2048 + kk*512 + lane*8);
    }

#pragma unroll
    for (int nt = 0; nt < 2; ++nt){
      float Ar[4], Br[4], Cc[4];
#pragma unroll
      for (int r = 0; r < 4; ++r){
        float dtv = softplus_f(acc[1][nt][r] + bDv[nt]);
        Ar[r] = __expf(dtv * Avv[nt]);
        Br[r] = dtv * (acc[0][nt][r] + bBv[nt]);
        Cc[r] = acc[2][nt][r] + bCv[nt];
      }
      // compose lane's 4-token segment
      float P = Ar[0], H = Br[0];
#pragma unroll
      for (int r = 1; r < 4; ++r){ H = Ar[r]*H + Br[r]; P *= Ar[r]; }
      // inclusive scan across q (2 steps)
      float pp = __shfl(P, (lane - 16) & 63, 64);
      float hh = __shfl(H, (lane - 16) & 63, 64);
      if (q >= 1){ H = P*hh + H; P *= pp; }
      pp = __shfl(P, (lane - 32) & 63, 64);
      hh = __shfl(H, (lane - 32) & 63, 64);
      if (q >= 2){ H = P*hh + H; P *= pp; }
      // exclusive prefix for this q
      float pe = __shfl(P, (lane - 16) & 63, 64);
      float he = __shfl(H, (lane - 16) & 63, 64);
      if (q == 0){ pe = 1.f; he = 0.f; }
      // tile totals broadcast (q==3 inclusive)
      float pb = __shfl(P, m + 48, 64);
      float hb = __shfl(H, m + 48, 64);

      float h = he, pa = pe;
      float ys[4], cs[4];
#pragma unroll
      for (int r = 0; r < 4; ++r){
        h = Ar[r]*h + Br[r];
        pa *= Ar[r];
        ys[r] = Cc[r]*h;
        cs[r] = Cc[r]*pa;
      }
      ypk[i][nt][0] = cvt_pk_bf16(ys[0], ys[1]);
      ypk[i][nt][1] = cvt_pk_bf16(ys[2], ys[3]);
      cpk[i][nt][0] = cvt_pk_bf16(cs[0], cs[1]);
      cpk[i][nt][1] = cvt_pk_bf16(cs[2], cs[3]);

      pe_t[i][nt] = pa_run[nt];
      he_t[i][nt] = ha_run[nt];
      ha_run[nt] = pb*ha_run[nt] + hb;
      pa_run[nt] *= pb;
    }
  }
  // publish wave totals per n (identical across q; q==0 writes)
  if (q == 0){
#pragma unroll
    for (int nt = 0; nt < 2; ++nt){
      sPw[wv][nt*16 + m] = pa_run[nt];
      sHw[wv][nt*16 + m] = ha_run[nt];
    }
  }
  __syncthreads();                           // sW dead from here

  // ---- Phase B: publish LOCAL aggregate, decoupled lookback (threads 0..31)
  if (tid < 32){
    float Pw[4], Hw[4];
#pragma unroll
    for (int w2 = 0; w2 < 4; ++w2){ Pw[w2] = sPw[w2][tid]; Hw[w2] = sHw[w2][tid]; }
    // block-local aggregate over the 4 waves
    float pb = 1.f, hb = 0.f;
#pragma unroll
    for (int w2 = 0; w2 < 4; ++w2){ hb = Pw[w2]*hb + Hw[w2]; pb *= Pw[w2]; }
    // single-word publish: [P|H]; validity = P bits != 0 (P>0, clamped)
    float pbc = fmaxf(pb, 1e-30f);
    __hip_atomic_store(Sbuf + (size_t)(by*16 + bx)*32 + tid,
        ((unsigned long long)__float_as_uint(pbc) << 32) |
         (unsigned long long)__float_as_uint(hb),
        __ATOMIC_RELAXED, __HIP_MEMORY_SCOPE_AGENT);
    // gather ALL predecessors' locals concurrently. Backoff sleep: waiters
    // must NOT flood L2 with polls -- that starves workers' xp loads.
    float S = 0.f;
    const int cnt = bx & 7;                // # predecessors within batch row
    if (cnt){
      const int j0 = bx & ~7;
      unsigned long long v0=0,v1=0,v2=0,v3=0,v4=0,v5=0,v6=0;
      unsigned got = 0;
      int spin = 0;
      const unsigned all = (1u << cnt) - 1u;
      const unsigned long long* base = Sbuf + (size_t)(by*16 + j0)*32 + tid;
      for (;;){
#define LOOKBACK(J, V)                                                          \
        if (J < cnt && !(got & (1u << J))){                                     \
          unsigned long long a = __hip_atomic_load(base + (size_t)J*32,         \
              __ATOMIC_RELAXED, __HIP_MEMORY_SCOPE_AGENT);                      \
          if ((unsigned)(a >> 32) != 0u){ V = a; got |= 1u << J; }              \
        }
        LOOKBACK(0, v0) LOOKBACK(1, v1) LOOKBACK(2, v2) LOOKBACK(3, v3)
        LOOKBACK(4, v4) LOOKBACK(5, v5) LOOKBACK(6, v6)
#undef LOOKBACK
        if (got == all) break;
        if (spin < 4)       __builtin_amdgcn_s_sleep(2);
        else if (spin < 8)  __builtin_amdgcn_s_sleep(8);
        else                __builtin_amdgcn_s_sleep(32);
        ++spin;
      }
      // ordered composition j0..bx-1: S = P_j*S + H_j
#define COMPOSE(J, V)                                                           \
      if (J < cnt) S = __uint_as_float((unsigned)(V >> 32))*S +                 \
                       __uint_as_float((unsigned)V);
      COMPOSE(0, v0) COMPOSE(1, v1) COMPOSE(2, v2) COMPOSE(3, v3)
      COMPOSE(4, v4) COMPOSE(5, v5) COMPOSE(6, v6)
#undef COMPOSE
    }
    // per-wave init states
    float s = S;
#pragma unroll
    for (int w2 = 0; w2 < 4; ++w2){
      sIw[w2][tid] = s;
      s = Pw[w2]*s + Hw[w2];
    }
  }
  __syncthreads();                           // sYT (alias of sW) live from here

  // ---- Phase C: fixup + transpose + store
  float iw[2];
#pragma unroll
  for (int nt = 0; nt < 2; ++nt) iw[nt] = sIw[wv][nt*16 + m];
#pragma unroll
  for (int i = 0; i < 4; ++i){
    const int tile = bx*16 + wv*4 + i;
#pragma unroll
    for (int nt = 0; nt < 2; ++nt){
      float it = pe_t[i][nt]*iw[nt] + he_t[i][nt];
#pragma unroll
      for (int j2 = 0; j2 < 2; ++j2){
        unsigned yp = ypk[i][nt][j2], cp = cpk[i][nt][j2];
        float y0 = __uint_as_float(yp << 16);
        float y1 = __uint_as_float(yp & 0xffff0000u);
        float c0 = __uint_as_float(cp << 16);
        float c1 = __uint_as_float(cp & 0xffff0000u);
        sYT[(q*4 + j2*2 + 0)*40 + nt*16 + m] = f2b(y0 + c0*it);
        sYT[(q*4 + j2*2 + 1)*40 + nt*16 + m] = f2b(y1 + c1*it);
      }
    }
    short8 yv = *(const short8*)&sYT[m*40 + q*8];
    *(short8*)(ybp + (size_t)tile*32768 + (size_t)by*512 + (size_t)lane*8) = yv;
  }
}

// ---------------- 3. output projection, d-split ----------------
// grid (NTILE, 2), block 256. Block (tile, half) computes d-tiles
// dt = half*4 .. half*4+3. Wave wv: kk in [wv*16, wv*16+16).
// Per block: 4 waves x 16 kk x 4 dt = 256 MFMA, Wop footprint 0.25 MB,
// LDS 16 KB -> 2 blocks/CU: the R19-validated latency-hiding config
// (R20's 8-wave x 8-step variant tested null-to-negative).
__global__ void outproj_kernel(const unsigned short* __restrict__ ybp,
                               const unsigned short* __restrict__ Wop,
                               const float* __restrict__ b_out,
                               float* __restrict__ out){
  __shared__ float red[4*1024];          // 4 waves x 16 tl x 64 d_local
  const int tid  = threadIdx.x;
  const int lane = tid & 63;
  const int wv   = tid >> 6;
  const int m    = lane & 15;
  const int q    = lane >> 4;
  const int tile = blockIdx.x;
  const int half = blockIdx.y;           // d-half: dt = half*4 + dtl

  floatx4 acc[4];
#pragma unroll
  for (int dtl = 0; dtl < 4; ++dtl) acc[dtl] = (floatx4){0.f,0.f,0.f,0.f};

  const unsigned short* aP = ybp + (size_t)tile*32768 + lane*8;
  const unsigned short* bP = Wop + (size_t)(half*4)*32768 + lane*8;
#pragma unroll 4
  for (int kk = wv*16; kk < wv*16 + 16; ++kk){
    short8 af = *(const short8*)(aP + (size_t)kk*512);
#pragma unroll
    for (int dtl = 0; dtl < 4; ++dtl){
      short8 bf = *(const short8*)(bP + (size_t)dtl*32768 + (size_t)kk*512);
      acc[dtl] = __builtin_amdgcn_mfma_f32_16x16x32_bf16(af, bf, acc[dtl], 0, 0, 0);
    }
  }
#pragma unroll
  for (int dtl = 0; dtl < 4; ++dtl)
#pragma unroll
    for (int r = 0; r < 4; ++r)
      red[wv*1024 + (q*4 + r)*64 + dtl*16 + m] = acc[dtl][r];
  __syncthreads();
#pragma unroll
  for (int i = 0; i < 4; ++i){
    int idx = i*256 + tid;                        // 0..1023 = tl*64 + dl
    float s = red[idx] + red[1024 + idx] + red[2048 + idx] + red[3072 + idx];
    int tl = idx >> 6, dl = idx & 63;
    int d = half*64 + dl;
    out[(size_t)(tile*16 + tl)*DDIM + d] = s + b_out[d];
  }
}

extern "C" void kernel_launch(void* const* d_in, const int* in_sizes, int n_in,
                              void* d_out, int out_size, void* d_ws, size_t ws_size,
                              hipStream_t stream) {
  const float* x     = (const float*)d_in[0];
  const float* W_B   = (const float*)d_in[1];
  const float* b_B   = (const float*)d_in[2];
  const float* W_C   = (const float*)d_in[3];
  const float* b_C   = (const float*)d_in[4];
  const float* W_dt  = (const float*)d_in[5];
  const float* b_dt  = (const float*)d_in[6];
  const float* A_log = (const float*)d_in[7];
  const float* W_out = (const float*)d_in[8];
  const float* b_out = (const float*)d_in[9];
  float* out = (float*)d_out;

  char* w = (char*)d_ws;
  unsigned short* xp    = (unsigned short*)(w + 0x0000000);  // 1 MB
  unsigned short* Wp3   = (unsigned short*)(w + 0x0100000);  // 1.5 MB
  unsigned short* Wop   = (unsigned short*)(w + 0x0280000);  // 0.5 MB
  float*          Aval  = (float*)         (w + 0x0300000);  // 8 KB
  unsigned short* ybp   = (unsigned short*)(w + 0x0310000);  // 16 MB
  unsigned long long* Sbuf = (unsigned long long*)(w + 0x1310000); // 256 KB
  // total ~19.7 MB

  prep_kernel<<<384, 256, 0, stream>>>(
      x, W_B, W_C, W_dt, A_log, W_out, xp, Wp3, Wop, Aval, Sbuf);

  projscan_kernel<<<dim3(16, 64), 256, 0, stream>>>(
      xp, Wp3, b_B, b_dt, b_C, Aval, Sbuf, ybp);

  outproj_kernel<<<dim3(NTILE, 2), 256, 0, stream>>>(ybp, Wop, b_out, out);
}